// Round 3
// baseline (444.432 us; speedup 1.0000x reference)
//
#include <hip/hip_runtime.h>
#include <stdint.h>

// Problem constants (B=8,T=8192,H=512,E=4,R=16)
#define NTOK 65536
#define HD   512
#define EXP  4
#define RK   16

typedef __attribute__((ext_vector_type(8)))  short short8;
typedef __attribute__((ext_vector_type(4)))  float f32x4;
typedef __attribute__((ext_vector_type(16))) float f32x16;

__device__ __forceinline__ unsigned short f2bf(float f) {
  union { float f; unsigned int u; } c; c.f = f;
  return (unsigned short)((c.u + 0x7fffu + ((c.u >> 16) & 1u)) >> 16);
}

__device__ __forceinline__ void gl_lds16(const void* g, void* l) {
  __builtin_amdgcn_global_load_lds((const __attribute__((address_space(1))) void*)g,
                                   (__attribute__((address_space(3))) void*)l, 16, 0, 0);
}

// ---------------- fused x fp32->bf16 + gating (reads x ONCE) ----------------
__global__ void convgate(const float* __restrict__ x, const float* __restrict__ gw,
                         const float* __restrict__ tw, unsigned short* __restrict__ xbo,
                         float* __restrict__ gates) {
  const int lane = threadIdx.x & 63;
  const int n = blockIdx.x * 4 + (threadIdx.x >> 6);
  const float4* xr = (const float4*)(x + (size_t)n * HD);
  const float4 xa = xr[lane * 2], xb = xr[lane * 2 + 1];
  ushort4 ua, ub;
  ua.x = f2bf(xa.x); ua.y = f2bf(xa.y); ua.z = f2bf(xa.z); ua.w = f2bf(xa.w);
  ub.x = f2bf(xb.x); ub.y = f2bf(xb.y); ub.z = f2bf(xb.z); ub.w = f2bf(xb.w);
  ushort4* xo = (ushort4*)(xbo + (size_t)n * HD);
  xo[lane * 2] = ua; xo[lane * 2 + 1] = ub;
  float s[5];
#pragma unroll
  for (int e = 0; e < 4; e++) {
    const float4* wr = (const float4*)(gw + e * HD);
    const float4 wa = wr[lane * 2], wb = wr[lane * 2 + 1];
    s[e] = xa.x * wa.x + xa.y * wa.y + xa.z * wa.z + xa.w * wa.w
         + xb.x * wb.x + xb.y * wb.y + xb.z * wb.z + xb.w * wb.w;
  }
  {
    const float4* wr = (const float4*)tw;
    const float4 wa = wr[lane * 2], wb = wr[lane * 2 + 1];
    s[4] = xa.x * wa.x + xa.y * wa.y + xa.z * wa.z + xa.w * wa.w
         + xb.x * wb.x + xb.y * wb.y + xb.z * wb.z + xb.w * wb.w;
  }
#pragma unroll
  for (int off = 32; off > 0; off >>= 1)
#pragma unroll
    for (int i = 0; i < 5; i++) s[i] += __shfl_xor(s[i], off, 64);
  float m = fmaxf(fmaxf(s[0], s[1]), fmaxf(s[2], s[3]));
  float e0 = expf(s[0] - m), e1 = expf(s[1] - m), e2 = expf(s[2] - m), e3 = expf(s[3] - m);
  float inv = 1.f / (e0 + e1 + e2 + e3);
  float thr = 0.25f / (1.f + expf(-s[4]));
  float a0 = e0 * inv - thr, a1 = e1 * inv - thr, a2 = e2 * inv - thr, a3 = e3 * inv - thr;
  float w0 = a0 > 0.f ? a0 : 0.f, w1 = a1 > 0.f ? a1 : 0.f;
  float w2 = a2 > 0.f ? a2 : 0.f, w3 = a3 > 0.f ? a3 : 0.f;
  float wsum = w0 + w1 + w2 + w3;
  wsum = (wsum == 0.f) ? 1.f : wsum;
  if (lane < 4) {
    float wv = lane == 0 ? w0 : lane == 1 ? w1 : lane == 2 ? w2 : w3;
    gates[(size_t)n * 4 + lane] = wv / wsum;
  }
}

// ---------------- bulk fp32 -> bf16 (fc1_w) ----------------
__global__ void convk(const float* __restrict__ in, unsigned short* __restrict__ o, int n4) {
  int i = blockIdx.x * 256 + threadIdx.x;
  if (i < n4) {
    float4 v = ((const float4*)in)[i];
    ushort4 u;
    u.x = f2bf(v.x); u.y = f2bf(v.y); u.z = f2bf(v.z); u.w = f2bf(v.w);
    ((ushort4*)o)[i] = u;
  }
}

// ---------------- Mt[d][e*16+r] = sum_o lora_B[e,r,o] * fc2_w[e,d,o] ----------------
__global__ void prep_mt(const float* __restrict__ loraB, const float* __restrict__ fc2,
                        unsigned short* __restrict__ Mt) {
  int idx = blockIdx.x * 256 + threadIdx.x;  // 64*512 = 32768 threads
  int d  = idx & (HD - 1);
  int er = idx >> 9;
  int e = er >> 4, r = er & 15;
  const float4* B = (const float4*)(loraB + ((size_t)e * RK + r) * HD);
  const float4* F = (const float4*)(fc2 + ((size_t)e * HD + d) * HD);
  float a0 = 0.f, a1 = 0.f, a2 = 0.f, a3 = 0.f;
  for (int i = 0; i < HD / 4; i += 4) {
    float4 b0 = B[i],     f0 = F[i];
    float4 b1 = B[i + 1], f1 = F[i + 1];
    float4 b2 = B[i + 2], f2 = F[i + 2];
    float4 b3 = B[i + 3], f3 = F[i + 3];
    a0 += b0.x * f0.x + b0.y * f0.y + b0.z * f0.z + b0.w * f0.w;
    a1 += b1.x * f1.x + b1.y * f1.y + b1.z * f1.z + b1.w * f1.w;
    a2 += b2.x * f2.x + b2.y * f2.y + b2.z * f2.z + b2.w * f2.w;
    a3 += b3.x * f3.x + b3.y * f3.y + b3.z * f3.z + b3.w * f3.w;
  }
  Mt[d * 64 + er] = f2bf(a0 + a1 + a2 + a3);
}

// ---------------- laT[e][r][h] = bf16(lora_A[e][h][r]) ----------------
// lets fc1_lora's LoRA stage load B-fragments as short8 instead of 64 scalar f32 loads
__global__ void prep_la(const float* __restrict__ la, unsigned short* __restrict__ laT) {
  int idx = blockIdx.x * 256 + threadIdx.x;  // 64*512 = 32768 threads
  int h = idx & (HD - 1);
  int er = idx >> 9;                         // e*16+r
  int e = er >> 4, r = er & 15;
  laT[(size_t)er * HD + h] = f2bf(la[((size_t)e * HD + h) * RK + r]);
}

// ---------------- fused fc1 + relu + lora_A -> lw[N][64] (atomic fp32) ----------------
// Round-3 restructure: the round-2 kernel was ONE 8-wave block/CU in barrier lockstep
// (232 unified regs/thread -> 2 waves/SIMD; 132KB LDS -> 1 block/CU). Both waves on a
// SIMD issued their ds_reads together; nothing fed the MFMA pipe during the read
// window -> 38% MfmaUtil. Fix: 256-thread / 4-wave blocks (2x2 wave grid, per-wave
// STILL 128x64 = 4x2 frags of 32x32 -> 768 B LDS per MFMA), tile 256tok x 128h,
// BK=32, ring-3 LDS (3 x 24KB) + hsm[256][136] overlap = 73.7KB -> 2 INDEPENDENT
// blocks/CU. When block A waits at its boundary, block B's waves run MFMA.
// Barriers: ONE per K-tile (boundary only; intra-tile phases have no LDS hazard).
// Counted vmcnt: stage 2 tiles ahead, vmcnt(6) steady state, drain only at t=14.
//
// LDS swizzle (proven in round 2): 2 token rows per 128-B super-row,
// slot = sr*8 + (g8 ^ (sr&7)), g8 = (row&1)*4 + g. Every consecutive-8-lane phase
// of a wave64 ds_read_b128 tiles all 32 banks exactly once.
//
// XCD decode: XCD = bid%8; eh fastest within XCD -> the 16 (e,hq) blocks of one
// token tile run back-to-back on ONE XCD; x-tile fetched from HBM once per XCD.
__launch_bounds__(256, 2)
__global__ void fc1_lora(const unsigned short* __restrict__ xb,
                         const unsigned short* __restrict__ w1b,
                         const unsigned short* __restrict__ laT,
                         float* __restrict__ lw) {
  __shared__ __align__(16) char smem[73728];  // ring: 3x24576; epilogue hsm: 256x136x2
  const int bid = blockIdx.x;           // 4096 blocks
  const int c = bid & 7;                // XCD
  const int j = bid >> 3;               // 0..511 within XCD
  const int eh = j & 15;
  const int e = eh >> 2, hq = eh & 3;   // expert, h-quarter (128 h each)
  const int ntile = c * 32 + (j >> 4);
  const int n0 = ntile * 256;
  const int tid = threadIdx.x;
  const int wave = tid >> 6, lane = tid & 63;
  const int l16 = lane & 15, quad = lane >> 4;
  const int l32 = lane & 31, half = lane >> 5;
  const int wr = wave >> 1, wc = wave & 1;   // 2M x 2N wave grid (each 128x64 out)

  const unsigned short* xg = xb + (size_t)n0 * HD;
  const unsigned short* wg = w1b + ((size_t)e * HD + (size_t)hq * 128) * HD;

  // staging sources (pre-swizzled): slot S = tid + 256*i; sr = S>>3,
  // g8 = (S&7)^(sr&7), row = sr*2 + (g8>>2), granule = g8&3
  const unsigned short* xsrc[4];   // A: 256 rows x 32k = 1024 slots
  const unsigned short* wsrc[2];   // B: 128 rows x 32k =  512 slots
#pragma unroll
  for (int i = 0; i < 4; i++) {
    const int sl = tid + 256 * i;
    const int sr = sl >> 3, g8 = (sl & 7) ^ (sr & 7);
    const int row = sr * 2 + (g8 >> 2), g = g8 & 3;
    xsrc[i] = xg + (size_t)row * HD + g * 8;
  }
#pragma unroll
  for (int i = 0; i < 2; i++) {
    const int sl = tid + 256 * i;
    const int sr = sl >> 3, g8 = (sl & 7) ^ (sr & 7);
    const int row = sr * 2 + (g8 >> 2), g = g8 & 3;
    wsrc[i] = wg + (size_t)row * HD + g * 8;
  }

  // loop-invariant LDS read byte offsets: [phase][frag]; needed granule = p*2+half
  int axo[2][4], bxo[2][2];
#pragma unroll
  for (int p = 0; p < 2; p++) {
#pragma unroll
    for (int mb = 0; mb < 4; mb++) {
      const int rowa = wr * 128 + mb * 32 + l32;
      const int sr = rowa >> 1, g8 = (rowa & 1) * 4 + p * 2 + half;
      axo[p][mb] = (sr * 8 + (g8 ^ (sr & 7))) * 16;
    }
#pragma unroll
    for (int nb = 0; nb < 2; nb++) {
      const int rowb = wc * 64 + nb * 32 + l32;
      const int sr = rowb >> 1, g8 = (rowb & 1) * 4 + p * 2 + half;
      bxo[p][nb] = (sr * 8 + (g8 ^ (sr & 7))) * 16;
    }
  }

  f32x16 acc[4][2];
#pragma unroll
  for (int mb = 0; mb < 4; mb++)
#pragma unroll
    for (int nb = 0; nb < 2; nb++)
#pragma unroll
      for (int r = 0; r < 16; r++) acc[mb][nb][r] = 0.f;

  // prologue: stage K-tiles 0,1 into ring slots 0,1 (6 gl_lds/wave/tile)
#pragma unroll
  for (int tt = 0; tt < 2; tt++) {
    char* As = smem + tt * 24576;
#pragma unroll
    for (int i = 0; i < 4; i++) gl_lds16(xsrc[i] + tt * 32, As + (256 * i + wave * 64) * 16);
#pragma unroll
    for (int i = 0; i < 2; i++) gl_lds16(wsrc[i] + tt * 32, As + 16384 + (256 * i + wave * 64) * 16);
  }
  asm volatile("s_waitcnt vmcnt(6)\n\ts_barrier" ::: "memory");  // tile0 resident
  __builtin_amdgcn_sched_barrier(0);

  // main loop: 16 K-tiles of 32; ONE barrier per tile; vmcnt never 0 until t=14
#pragma unroll
  for (int t = 0; t < 16; t++) {
    char* Ab = smem + (t % 3) * 24576;
    char* Bb = Ab + 16384;
    if (t < 14) {  // stage tile t+2 into the slot freed at the (t-1)->t boundary
      char* As = smem + ((t + 2) % 3) * 24576;
      const int kos = (t + 2) * 32;
#pragma unroll
      for (int i = 0; i < 4; i++) gl_lds16(xsrc[i] + kos, As + (256 * i + wave * 64) * 16);
#pragma unroll
      for (int i = 0; i < 2; i++) gl_lds16(wsrc[i] + kos, As + 16384 + (256 * i + wave * 64) * 16);
    }
#pragma unroll
    for (int p = 0; p < 2; p++) {
      short8 af[4], bf[2];
#pragma unroll
      for (int mb = 0; mb < 4; mb++) af[mb] = *(const short8*)(Ab + axo[p][mb]);
#pragma unroll
      for (int nb = 0; nb < 2; nb++) bf[nb] = *(const short8*)(Bb + bxo[p][nb]);
      __builtin_amdgcn_s_setprio(1);
#pragma unroll
      for (int mb = 0; mb < 4; mb++)
#pragma unroll
        for (int nb = 0; nb < 2; nb++)
          acc[mb][nb] = __builtin_amdgcn_mfma_f32_32x32x16_bf16(af[mb], bf[nb], acc[mb][nb], 0, 0, 0);
      __builtin_amdgcn_s_setprio(0);
    }
    // boundary: tile t+1 must be resident; newest-6 outstanding = tile t+2's loads
    if (t < 14) {
      asm volatile("s_waitcnt lgkmcnt(0)\n\ts_waitcnt vmcnt(6)\n\ts_barrier" ::: "memory");
    } else if (t == 14) {
      asm volatile("s_waitcnt lgkmcnt(0)\n\ts_waitcnt vmcnt(0)\n\ts_barrier" ::: "memory");
    } else {
      asm volatile("s_waitcnt lgkmcnt(0)\n\ts_barrier" ::: "memory");
    }
    __builtin_amdgcn_sched_barrier(0);
  }

  // stage 2: relu -> bf16 hidden to block-shared LDS [256 tok][136 shorts]
  unsigned short* hsm = (unsigned short*)smem;
#pragma unroll
  for (int mb = 0; mb < 4; mb++)
#pragma unroll
    for (int nb = 0; nb < 2; nb++) {
      const int colh = wc * 64 + nb * 32 + l32;
#pragma unroll
      for (int r = 0; r < 16; r++) {
        const int tok = wr * 128 + mb * 32 + 4 * half + (r & 3) + 8 * (r >> 2);
        float v = acc[mb][nb][r];
        v = v > 0.f ? v : 0.f;
        hsm[tok * 136 + colh] = f2bf(v);
      }
    }
  __syncthreads();

  // lo[tok][r] over this block's 128 h; wave handles tokens wave*64..+63
  const unsigned short* laTe = laT + (size_t)(e * 16 + l16) * HD + hq * 128;
  f32x4 lo[4];
#pragma unroll
  for (int mf = 0; mf < 4; mf++)
#pragma unroll
    for (int i = 0; i < 4; i++) lo[mf][i] = 0.f;
#pragma unroll
  for (int k2 = 0; k2 < 4; k2++) {
    const short8 b2 = *(const short8*)(laTe + k2 * 32 + quad * 8);
#pragma unroll
    for (int mf = 0; mf < 4; mf++) {
      const int tok = wave * 64 + mf * 16 + l16;
      const short8 a2 = *(const short8*)(hsm + tok * 136 + k2 * 32 + quad * 8);
      lo[mf] = __builtin_amdgcn_mfma_f32_16x16x32_bf16(a2, b2, lo[mf], 0, 0, 0);
    }
  }
#pragma unroll
  for (int mf = 0; mf < 4; mf++)
#pragma unroll
    for (int i = 0; i < 4; i++)
      atomicAdd(lw + (size_t)(n0 + wave * 64 + mf * 16 + quad * 4 + i) * 64 + e * 16 + l16, lo[mf][i]);
}

// ---------------- combine: out[n][d] = sum_k (lw[n][k]*gate[n][k/16]) * Mt[d][k] ----------------
// Mt staged into LDS with full-period XOR-swizzled 16B granules (conflict-free).
__launch_bounds__(256, 2)
__global__ void combine_k(const float* __restrict__ lw, const float* __restrict__ gates,
                          const unsigned short* __restrict__ Mt, float* __restrict__ out) {
  __shared__ __align__(16) char smem[65536];
  const int n0 = blockIdx.x * 64;
  const int tid = threadIdx.x;
  const int wave = tid >> 6, lane = tid & 63, quad = lane >> 4, l16 = lane & 15;
#pragma unroll
  for (int i = 0; i < 16; i++) {
    const int slot = tid + 256 * i;          // 0..4095
    const int row = slot >> 3;
    const int g = (slot & 7) ^ (row & 7);
    *(uint4*)(smem + slot * 16) = *(const uint4*)(Mt + row * 64 + g * 8);
  }
  __syncthreads();
  f32x4 acc[4][8];
#pragma unroll
  for (int a = 0; a < 4; a++)
#pragma unroll
    for (int b = 0; b < 8; b++)
#pragma unroll
      for (int i = 0; i < 4; i++) acc[a][b][i] = 0.f;
#pragma unroll
  for (int ks = 0; ks < 2; ks++) {
    short8 af[4], bfr[8];
#pragma unroll
    for (int mf = 0; mf < 4; mf++) {
      const int n = n0 + mf * 16 + l16;
      const float* lr = lw + (size_t)n * 64 + ks * 32 + quad * 8;
      float4 u0 = *(const float4*)lr;
      float4 u1 = *(const float4*)(lr + 4);
      const float g = gates[(size_t)n * 4 + ((ks * 32 + quad * 8) >> 4)];
      union { short8 v; unsigned short s[8]; } a;
      a.s[0] = f2bf(u0.x * g); a.s[1] = f2bf(u0.y * g);
      a.s[2] = f2bf(u0.z * g); a.s[3] = f2bf(u0.w * g);
      a.s[4] = f2bf(u1.x * g); a.s[5] = f2bf(u1.y * g);
      a.s[6] = f2bf(u1.z * g); a.s[7] = f2bf(u1.w * g);
      af[mf] = a.v;
    }
#pragma unroll
    for (int nf = 0; nf < 8; nf++) {
      const int row = wave * 128 + nf * 16 + l16;
      const int slot = row * 8 + ((ks * 4 + quad) ^ (row & 7));
      bfr[nf] = *(const short8*)(smem + slot * 16);
    }
#pragma unroll
    for (int mf = 0; mf < 4; mf++)
#pragma unroll
      for (int nf = 0; nf < 8; nf++)
        acc[mf][nf] = __builtin_amdgcn_mfma_f32_16x16x32_bf16(af[mf], bfr[nf], acc[mf][nf], 0, 0, 0);
  }
#pragma unroll
  for (int mf = 0; mf < 4; mf++)
#pragma unroll
    for (int nf = 0; nf < 8; nf++) {
      const int d = wave * 128 + nf * 16 + l16;
#pragma unroll
      for (int i = 0; i < 4; i++)
        out[(size_t)(n0 + mf * 16 + quad * 4 + i) * HD + d] = acc[mf][nf][i];
    }
}

// ---------------- launch ----------------
extern "C" void kernel_launch(void* const* d_in, const int* in_sizes, int n_in,
                              void* d_out, int out_size, void* d_ws, size_t ws_size,
                              hipStream_t stream) {
  const float* x      = (const float*)d_in[0];
  const float* gate_w = (const float*)d_in[1];
  const float* thr_w  = (const float*)d_in[2];
  const float* fc1_w  = (const float*)d_in[3];
  const float* lora_A = (const float*)d_in[4];
  const float* lora_B = (const float*)d_in[5];
  const float* fc2_w  = (const float*)d_in[6];
  float* out = (float*)d_out;
  char* ws = (char*)d_ws;

  unsigned short* xbp = (unsigned short*)(ws);                   // 67108864 B
  unsigned short* w1b = (unsigned short*)(ws + 67108864);        //  2097152 B
  unsigned short* Mt  = (unsigned short*)(ws + 69206016);        //    65536 B
  float*          gts = (float*)(ws + 69271552);                 //  1048576 B
  float*          lwp = (float*)(ws + 70320128);                 // 16777216 B
  unsigned short* laT = (unsigned short*)(ws + 87097344);        //    65536 B

  hipMemsetAsync(lwp, 0, (size_t)NTOK * 64 * sizeof(float), stream);
  convgate<<<NTOK / 4, 256, 0, stream>>>(x, gate_w, thr_w, xbp, gts);
  convk<<<1024, 256, 0, stream>>>(fc1_w, w1b, EXP * HD * HD / 4);
  prep_mt<<<128, 256, 0, stream>>>(lora_B, fc2_w, Mt);
  prep_la<<<128, 256, 0, stream>>>(lora_A, laT);
  fc1_lora<<<4096, 256, 0, stream>>>(xbp, w1b, laT, lwp);
  combine_k<<<NTOK / 64, 256, 0, stream>>>(lwp, gts, Mt, out);
}

// Round 5
// 441.436 us; speedup vs baseline: 1.0068x; 1.0068x over previous
//
#include <hip/hip_runtime.h>
#include <stdint.h>

// Problem constants (B=8,T=8192,H=512,E=4,R=16)
#define NTOK 65536
#define HD   512
#define EXP  4
#define RK   16

typedef __attribute__((ext_vector_type(8)))  short short8;
typedef __attribute__((ext_vector_type(4)))  float f32x4;
typedef __attribute__((ext_vector_type(16))) float f32x16;

__device__ __forceinline__ unsigned short f2bf(float f) {
  union { float f; unsigned int u; } c; c.f = f;
  return (unsigned short)((c.u + 0x7fffu + ((c.u >> 16) & 1u)) >> 16);
}

__device__ __forceinline__ void gl_lds16(const void* g, void* l) {
  __builtin_amdgcn_global_load_lds((const __attribute__((address_space(1))) void*)g,
                                   (__attribute__((address_space(3))) void*)l, 16, 0, 0);
}

// ---------------- fused x fp32->bf16 + gating (reads x ONCE) ----------------
__global__ void convgate(const float* __restrict__ x, const float* __restrict__ gw,
                         const float* __restrict__ tw, unsigned short* __restrict__ xbo,
                         float* __restrict__ gates) {
  const int lane = threadIdx.x & 63;
  const int n = blockIdx.x * 4 + (threadIdx.x >> 6);
  const float4* xr = (const float4*)(x + (size_t)n * HD);
  const float4 xa = xr[lane * 2], xb = xr[lane * 2 + 1];
  ushort4 ua, ub;
  ua.x = f2bf(xa.x); ua.y = f2bf(xa.y); ua.z = f2bf(xa.z); ua.w = f2bf(xa.w);
  ub.x = f2bf(xb.x); ub.y = f2bf(xb.y); ub.z = f2bf(xb.z); ub.w = f2bf(xb.w);
  ushort4* xo = (ushort4*)(xbo + (size_t)n * HD);
  xo[lane * 2] = ua; xo[lane * 2 + 1] = ub;
  float s[5];
#pragma unroll
  for (int e = 0; e < 4; e++) {
    const float4* wr = (const float4*)(gw + e * HD);
    const float4 wa = wr[lane * 2], wb = wr[lane * 2 + 1];
    s[e] = xa.x * wa.x + xa.y * wa.y + xa.z * wa.z + xa.w * wa.w
         + xb.x * wb.x + xb.y * wb.y + xb.z * wb.z + xb.w * wb.w;
  }
  {
    const float4* wr = (const float4*)tw;
    const float4 wa = wr[lane * 2], wb = wr[lane * 2 + 1];
    s[4] = xa.x * wa.x + xa.y * wa.y + xa.z * wa.z + xa.w * wa.w
         + xb.x * wb.x + xb.y * wb.y + xb.z * wb.z + xb.w * wb.w;
  }
#pragma unroll
  for (int off = 32; off > 0; off >>= 1)
#pragma unroll
    for (int i = 0; i < 5; i++) s[i] += __shfl_xor(s[i], off, 64);
  float m = fmaxf(fmaxf(s[0], s[1]), fmaxf(s[2], s[3]));
  float e0 = expf(s[0] - m), e1 = expf(s[1] - m), e2 = expf(s[2] - m), e3 = expf(s[3] - m);
  float inv = 1.f / (e0 + e1 + e2 + e3);
  float thr = 0.25f / (1.f + expf(-s[4]));
  float a0 = e0 * inv - thr, a1 = e1 * inv - thr, a2 = e2 * inv - thr, a3 = e3 * inv - thr;
  float w0 = a0 > 0.f ? a0 : 0.f, w1 = a1 > 0.f ? a1 : 0.f;
  float w2 = a2 > 0.f ? a2 : 0.f, w3 = a3 > 0.f ? a3 : 0.f;
  float wsum = w0 + w1 + w2 + w3;
  wsum = (wsum == 0.f) ? 1.f : wsum;
  if (lane < 4) {
    float wv = lane == 0 ? w0 : lane == 1 ? w1 : lane == 2 ? w2 : w3;
    gates[(size_t)n * 4 + lane] = wv / wsum;
  }
}

// ---------------- bulk fp32 -> bf16 (fc1_w) ----------------
__global__ void convk(const float* __restrict__ in, unsigned short* __restrict__ o, int n4) {
  int i = blockIdx.x * 256 + threadIdx.x;
  if (i < n4) {
    float4 v = ((const float4*)in)[i];
    ushort4 u;
    u.x = f2bf(v.x); u.y = f2bf(v.y); u.z = f2bf(v.z); u.w = f2bf(v.w);
    ((ushort4*)o)[i] = u;
  }
}

// ---------------- Mt[d][e*16+r] = sum_o lora_B[e,r,o] * fc2_w[e,d,o] ----------------
// Round-4 fix: WAVE per output (old version: thread per output = each lane streaming
// its own 2-KB fc2 row -> fully uncoalesced, 128 blocks = 1/4 GPU). Now 64 lanes
// stride o -> coalesced float4 reads, shfl-reduce, 8192 blocks (full GPU).
__global__ void prep_mt(const float* __restrict__ loraB, const float* __restrict__ fc2,
                        unsigned short* __restrict__ Mt) {
  const int wid = blockIdx.x * 4 + (threadIdx.x >> 6);  // 0..32767
  const int lane = threadIdx.x & 63;
  const int d = wid & (HD - 1);
  const int er = wid >> 9;
  const int e = er >> 4, r = er & 15;
  const float4* B = (const float4*)(loraB + ((size_t)e * RK + r) * HD);
  const float4* F = (const float4*)(fc2 + ((size_t)e * HD + d) * HD);
  const float4 b0 = B[lane * 2], b1 = B[lane * 2 + 1];
  const float4 f0 = F[lane * 2], f1 = F[lane * 2 + 1];
  float s = b0.x * f0.x + b0.y * f0.y + b0.z * f0.z + b0.w * f0.w
          + b1.x * f1.x + b1.y * f1.y + b1.z * f1.z + b1.w * f1.w;
#pragma unroll
  for (int off = 32; off > 0; off >>= 1) s += __shfl_xor(s, off, 64);
  if (lane == 0) Mt[d * 64 + er] = f2bf(s);
}

// ---------------- laT[e][r][h] = bf16(lora_A[e][h][r]) ----------------
__global__ void prep_la(const float* __restrict__ la, unsigned short* __restrict__ laT) {
  int idx = blockIdx.x * 256 + threadIdx.x;  // 64*512 = 32768 threads
  int h = idx & (HD - 1);
  int er = idx >> 9;                         // e*16+r
  int e = er >> 4, r = er & 15;
  laT[(size_t)er * HD + h] = f2bf(la[((size_t)e * HD + h) * RK + r]);
}

// ---------------- fused fc1 + relu + lora_A -> lw[N][64] (atomic fp32) ----------------
// Round-4: 8-wave 256x256 shape (m201's exact regime: 512 thr, 1 block/CU,
// 2 waves/SIMD) with both round-2 bugs fixed, plus the full m201 per-phase schedule:
//   phase: {6 ds_read -> 2 gl_lds stage -> s_barrier -> lgkmcnt(0) ->
//           sched_barrier -> setprio(1) + 8 MFMA + setprio(0) -> s_barrier}
//   counted s_waitcnt vmcnt(8) ONCE per K-tile (at the tail of phase 1).
// Per wave 128x64 out = 4x2 frags of 32x32 (0.75 ds_read_b128/MFMA). Ring-4 LDS
// (4 x 32KB), staging 3 K-tiles ahead; vmcnt never 0 until the tail.
//
// LDS swizzle (proven round 3): 2 token rows per 128-B super-row,
// slot = sr*8 + (g8 ^ (sr&7)), g8 = (row&1)*4 + gk. Each consecutive-8-lane
// phase of a wave64 ds_read_b128 tiles all 32 banks exactly once.
//
// XCD decode (proven round 3): XCD = bid%8 owns 32 contiguous ntiles; eh fastest
// within XCD -> the 8 (e,hq) blocks of a token tile run back-to-back on ONE XCD.
__launch_bounds__(512, 2)
__global__ void fc1_lora(const unsigned short* __restrict__ xb,
                         const unsigned short* __restrict__ w1b,
                         const unsigned short* __restrict__ laT,
                         float* __restrict__ lw) {
  __shared__ __align__(16) char smem[135168];  // ring: 4x32768; epilogue hsm: 256x264x2
  const int bid = blockIdx.x;           // 2048 blocks
  const int c = bid & 7;                // XCD
  const int j = bid >> 3;               // 0..255 within XCD
  const int eh = j & 7;
  const int e = eh >> 1, hq = eh & 1;   // expert, h-half (256 h each)
  const int ntile = c * 32 + (j >> 3);
  const int n0 = ntile * 256;
  const int tid = threadIdx.x;
  const int wave = tid >> 6, lane = tid & 63;
  const int l16 = lane & 15, quad = lane >> 4;
  const int l32 = lane & 31, half = lane >> 5;
  const int wr = wave >> 2, wc = wave & 3;   // 2M x 4N wave grid (each 128x64 out)

  const unsigned short* xg = xb + (size_t)n0 * HD;
  const unsigned short* wg = w1b + ((size_t)e * HD + (size_t)hq * 256) * HD;

  // staging sources (pre-swizzled): slot S = tid + 512*i; sr = S>>3,
  // g8 = (S&7)^(sr&7), row = sr*2 + (g8>>2), granule = g8&3
  const unsigned short* xsrc[2];
  const unsigned short* wsrc[2];
#pragma unroll
  for (int i = 0; i < 2; i++) {
    const int sl = tid + 512 * i;
    const int sr = sl >> 3, g8 = (sl & 7) ^ (sr & 7);
    const int row = sr * 2 + (g8 >> 2), g = g8 & 3;
    xsrc[i] = xg + (size_t)row * HD + g * 8;
    wsrc[i] = wg + (size_t)row * HD + g * 8;
  }
  const int wbase = wave * 1024;  // wave-uniform LDS byte base (lane*16 implicit)

  // loop-invariant LDS read byte offsets: [phase][frag]; needed granule = p*2+half
  int axo[2][4], bxo[2][2];
#pragma unroll
  for (int p = 0; p < 2; p++) {
#pragma unroll
    for (int mb = 0; mb < 4; mb++) {
      const int rowa = wr * 128 + mb * 32 + l32;
      const int sr = rowa >> 1, g8 = (rowa & 1) * 4 + p * 2 + half;
      axo[p][mb] = (sr * 8 + (g8 ^ (sr & 7))) * 16;
    }
#pragma unroll
    for (int nb = 0; nb < 2; nb++) {
      const int rowb = wc * 64 + nb * 32 + l32;
      const int sr = rowb >> 1, g8 = (rowb & 1) * 4 + p * 2 + half;
      bxo[p][nb] = (sr * 8 + (g8 ^ (sr & 7))) * 16;
    }
  }

  f32x16 acc[4][2];
#pragma unroll
  for (int mb = 0; mb < 4; mb++)
#pragma unroll
    for (int nb = 0; nb < 2; nb++)
#pragma unroll
      for (int r = 0; r < 16; r++) acc[mb][nb][r] = 0.f;

  // prologue: stage K-tiles 0,1,2 into ring slots 0,1,2 (4 loads/thread/tile)
#pragma unroll
  for (int tt = 0; tt < 3; tt++) {
    char* As = smem + tt * 32768;
#pragma unroll
    for (int i = 0; i < 2; i++) gl_lds16(xsrc[i] + tt * 32, As + wbase + 8192 * i);
#pragma unroll
    for (int i = 0; i < 2; i++) gl_lds16(wsrc[i] + tt * 32, As + 16384 + wbase + 8192 * i);
  }
  asm volatile("s_waitcnt vmcnt(8)" ::: "memory");  // tile0 resident
  __builtin_amdgcn_s_barrier();
  __builtin_amdgcn_sched_barrier(0);

  // main loop: 16 K-tiles of 32; 2 phases/tile, m201 barrier-pair per phase
#pragma unroll
  for (int t = 0; t < 16; t++) {
    char* Ab = smem + (t & 3) * 32768;
    char* Bb = Ab + 16384;
    char* As = smem + ((t + 3) & 3) * 32768;  // freed at the (t-1)->t boundary
    const int kos = (t + 3) * 32;
#pragma unroll
    for (int p = 0; p < 2; p++) {
      short8 af[4], bf[2];
#pragma unroll
      for (int mb = 0; mb < 4; mb++) af[mb] = *(const short8*)(Ab + axo[p][mb]);
#pragma unroll
      for (int nb = 0; nb < 2; nb++) bf[nb] = *(const short8*)(Bb + bxo[p][nb]);
      if (t < 13) {  // stage tile t+3 (2 loads/phase)
        gl_lds16(xsrc[p] + kos, As + wbase + 8192 * p);
        gl_lds16(wsrc[p] + kos, As + 16384 + wbase + 8192 * p);
      }
      __builtin_amdgcn_s_barrier();
      asm volatile("s_waitcnt lgkmcnt(0)" ::: "memory");
      __builtin_amdgcn_sched_barrier(0);
      __builtin_amdgcn_s_setprio(1);
#pragma unroll
      for (int mb = 0; mb < 4; mb++)
#pragma unroll
        for (int nb = 0; nb < 2; nb++)
          acc[mb][nb] = __builtin_amdgcn_mfma_f32_32x32x16_bf16(af[mb], bf[nb], acc[mb][nb], 0, 0, 0);
      __builtin_amdgcn_s_setprio(0);
      if (p == 0) {
        __builtin_amdgcn_s_barrier();
      } else {
        // K-tile boundary: tile t+1 must be resident (issued 2+ tiles ago).
        // outstanding newest-8 = tiles t+2,t+3.
        if (t < 13)       asm volatile("s_waitcnt vmcnt(8)" ::: "memory");
        else if (t == 13) asm volatile("s_waitcnt vmcnt(4)" ::: "memory");
        else if (t == 14) asm volatile("s_waitcnt vmcnt(0)" ::: "memory");
        __builtin_amdgcn_s_barrier();
      }
      __builtin_amdgcn_sched_barrier(0);
    }
  }

  // stage 2: relu -> bf16 hidden to block-shared LDS [256 tok][264 shorts]
  unsigned short* hsm = (unsigned short*)smem;
#pragma unroll
  for (int mb = 0; mb < 4; mb++)
#pragma unroll
    for (int nb = 0; nb < 2; nb++) {
      const int colh = wc * 64 + nb * 32 + l32;
#pragma unroll
      for (int r = 0; r < 16; r++) {
        const int tok = wr * 128 + mb * 32 + 4 * half + (r & 3) + 8 * (r >> 2);
        float v = acc[mb][nb][r];
        v = v > 0.f ? v : 0.f;
        hsm[tok * 264 + colh] = f2bf(v);
      }
    }
  __syncthreads();

  // lo[tok][r] over this block's 256 h; wave handles tokens wave*32..+31
  const unsigned short* laTe = laT + (size_t)(e * 16 + l16) * HD + hq * 256;
  f32x4 lo[2];
#pragma unroll
  for (int mf = 0; mf < 2; mf++)
#pragma unroll
    for (int i = 0; i < 4; i++) lo[mf][i] = 0.f;
#pragma unroll
  for (int k2 = 0; k2 < 8; k2++) {
    const short8 b2 = *(const short8*)(laTe + k2 * 32 + quad * 8);
#pragma unroll
    for (int mf = 0; mf < 2; mf++) {
      const int tok = wave * 32 + mf * 16 + l16;
      const short8 a2 = *(const short8*)(hsm + tok * 264 + k2 * 32 + quad * 8);
      lo[mf] = __builtin_amdgcn_mfma_f32_16x16x32_bf16(a2, b2, lo[mf], 0, 0, 0);
    }
  }
#pragma unroll
  for (int mf = 0; mf < 2; mf++)
#pragma unroll
    for (int i = 0; i < 4; i++)
      atomicAdd(lw + (size_t)(n0 + wave * 32 + mf * 16 + quad * 4 + i) * 64 + e * 16 + l16, lo[mf][i]);
}

// ---------------- combine: out[n][d] = sum_k (lw[n][k]*gate[n][k/16]) * Mt[d][k] ----------------
// Mt staged into LDS (XOR-swizzled granules, conflict-free). Round-4: epilogue
// transposes each 16x16 C-frag through LDS so stores are float4 (32 vector stores
// per thread instead of 128 scalar f32 stores -> 4x fewer store instructions).
__launch_bounds__(256, 2)
__global__ void combine_k(const float* __restrict__ lw, const float* __restrict__ gates,
                          const unsigned short* __restrict__ Mt, float* __restrict__ out) {
  __shared__ __align__(16) char smem[65536];
  const int n0 = blockIdx.x * 64;
  const int tid = threadIdx.x;
  const int wave = tid >> 6, lane = tid & 63, quad = lane >> 4, l16 = lane & 15;
#pragma unroll
  for (int i = 0; i < 16; i++) {
    const int slot = tid + 256 * i;          // 0..4095
    const int row = slot >> 3;
    const int g = (slot & 7) ^ (row & 7);
    *(uint4*)(smem + slot * 16) = *(const uint4*)(Mt + row * 64 + g * 8);
  }
  __syncthreads();
  f32x4 acc[4][8];
#pragma unroll
  for (int a = 0; a < 4; a++)
#pragma unroll
    for (int b = 0; b < 8; b++)
#pragma unroll
      for (int i = 0; i < 4; i++) acc[a][b][i] = 0.f;
#pragma unroll
  for (int ks = 0; ks < 2; ks++) {
    short8 af[4], bfr[8];
#pragma unroll
    for (int mf = 0; mf < 4; mf++) {
      const int n = n0 + mf * 16 + l16;
      const float* lr = lw + (size_t)n * 64 + ks * 32 + quad * 8;
      float4 u0 = *(const float4*)lr;
      float4 u1 = *(const float4*)(lr + 4);
      const float g = gates[(size_t)n * 4 + ((ks * 32 + quad * 8) >> 4)];
      union { short8 v; unsigned short s[8]; } a;
      a.s[0] = f2bf(u0.x * g); a.s[1] = f2bf(u0.y * g);
      a.s[2] = f2bf(u0.z * g); a.s[3] = f2bf(u0.w * g);
      a.s[4] = f2bf(u1.x * g); a.s[5] = f2bf(u1.y * g);
      a.s[6] = f2bf(u1.z * g); a.s[7] = f2bf(u1.w * g);
      af[mf] = a.v;
    }
#pragma unroll
    for (int nf = 0; nf < 8; nf++) {
      const int row = wave * 128 + nf * 16 + l16;
      const int slot = row * 8 + ((ks * 4 + quad) ^ (row & 7));
      bfr[nf] = *(const short8*)(smem + slot * 16);
    }
#pragma unroll
    for (int mf = 0; mf < 4; mf++)
#pragma unroll
      for (int nf = 0; nf < 8; nf++)
        acc[mf][nf] = __builtin_amdgcn_mfma_f32_16x16x32_bf16(af[mf], bfr[nf], acc[mf][nf], 0, 0, 0);
  }
  // epilogue: per-frag 16x16 transpose via per-wave LDS scratch -> float4 stores.
  __syncthreads();  // all waves done reading Mt region before scratch reuse
  float* scr = (float*)smem + wave * 320;   // [16][20] f32 (pad keeps float4 aligned)
#pragma unroll
  for (int mf = 0; mf < 4; mf++)
#pragma unroll
    for (int nf = 0; nf < 8; nf++) {
#pragma unroll
      for (int i = 0; i < 4; i++) scr[(quad * 4 + i) * 20 + l16] = acc[mf][nf][i];
      // same-wave LDS ordering: DS pipe is in-order per wave; compiler inserts lgkm waits
      float4 v = *(const float4*)(scr + l16 * 20 + quad * 4);
      *(float4*)(out + (size_t)(n0 + mf * 16 + l16) * HD + wave * 128 + nf * 16 + quad * 4) = v;
    }
}

// ---------------- launch ----------------
extern "C" void kernel_launch(void* const* d_in, const int* in_sizes, int n_in,
                              void* d_out, int out_size, void* d_ws, size_t ws_size,
                              hipStream_t stream) {
  const float* x      = (const float*)d_in[0];
  const float* gate_w = (const float*)d_in[1];
  const float* thr_w  = (const float*)d_in[2];
  const float* fc1_w  = (const float*)d_in[3];
  const float* lora_A = (const float*)d_in[4];
  const float* lora_B = (const float*)d_in[5];
  const float* fc2_w  = (const float*)d_in[6];
  float* out = (float*)d_out;
  char* ws = (char*)d_ws;

  unsigned short* xbp = (unsigned short*)(ws);                   // 67108864 B
  unsigned short* w1b = (unsigned short*)(ws + 67108864);        //  2097152 B
  unsigned short* Mt  = (unsigned short*)(ws + 69206016);        //    65536 B
  float*          gts = (float*)(ws + 69271552);                 //  1048576 B
  float*          lwp = (float*)(ws + 70320128);                 // 16777216 B
  unsigned short* laT = (unsigned short*)(ws + 87097344);        //    65536 B

  hipMemsetAsync(lwp, 0, (size_t)NTOK * 64 * sizeof(float), stream);
  convgate<<<NTOK / 4, 256, 0, stream>>>(x, gate_w, thr_w, xbp, gts);
  convk<<<1024, 256, 0, stream>>>(fc1_w, w1b, EXP * HD * HD / 4);
  prep_mt<<<8192, 256, 0, stream>>>(lora_B, fc2_w, Mt);
  prep_la<<<128, 256, 0, stream>>>(lora_A, laT);
  fc1_lora<<<2048, 512, 0, stream>>>(xbp, w1b, laT, lwp);
  combine_k<<<NTOK / 64, 256, 0, stream>>>(lwp, gts, Mt, out);
}

// Round 6
// 438.752 us; speedup vs baseline: 1.0129x; 1.0061x over previous
//
#include <hip/hip_runtime.h>
#include <stdint.h>

// Problem constants (B=8,T=8192,H=512,E=4,R=16)
#define NTOK 65536
#define HD   512
#define EXP  4
#define RK   16

typedef __attribute__((ext_vector_type(8)))  short short8;
typedef __attribute__((ext_vector_type(4)))  float f32x4;
typedef __attribute__((ext_vector_type(16))) float f32x16;

__device__ __forceinline__ unsigned short f2bf(float f) {
  union { float f; unsigned int u; } c; c.f = f;
  return (unsigned short)((c.u + 0x7fffu + ((c.u >> 16) & 1u)) >> 16);
}

__device__ __forceinline__ void gl_lds16(const void* g, void* l) {
  __builtin_amdgcn_global_load_lds((const __attribute__((address_space(1))) void*)g,
                                   (__attribute__((address_space(3))) void*)l, 16, 0, 0);
}

// ---------------- fused x fp32->bf16 + gating (reads x ONCE) ----------------
// Round-6 v2: 8 tokens/wave. Half-wave (32 lanes x 16 elems) per token, 2 tokens
// in flight per wave instruction, x4 outer iters with gate/thr weights in REGISTERS
// (loaded once, reused 8x). Shuffles 30 -> 12.5/token, exp issue cost /2,
// weight loads /8. Old version: 1 token/wave, 30 shfl + 5 expf + 10 weight-fl4
// re-loads per token -> VALU-bound.
__global__ void convgate(const float* __restrict__ x, const float* __restrict__ gw,
                         const float* __restrict__ tw, unsigned short* __restrict__ xbo,
                         float* __restrict__ gates) {
  const int tid = threadIdx.x;
  const int wave = tid >> 6, lane = tid & 63;
  const int half = lane >> 5, l32 = lane & 31;
  const int base = blockIdx.x * 32 + wave * 8;   // 8 tokens per wave

  // weights: lane covers elems [l32*16, l32*16+16) = 4 float4 per row
  float4 wv[5][4];
#pragma unroll
  for (int e = 0; e < 4; e++) {
    const float4* wr = (const float4*)(gw + e * HD);
#pragma unroll
    for (int j = 0; j < 4; j++) wv[e][j] = wr[l32 * 4 + j];
  }
  {
    const float4* wr = (const float4*)tw;
#pragma unroll
    for (int j = 0; j < 4; j++) wv[4][j] = wr[l32 * 4 + j];
  }

#pragma unroll
  for (int it = 0; it < 4; it++) {
    const int n = base + it * 2 + half;          // half-wave owns one token
    const float4* xr = (const float4*)(x + (size_t)n * HD);
    float4 xv[4];
#pragma unroll
    for (int j = 0; j < 4; j++) xv[j] = xr[l32 * 4 + j];

    // bf16 convert + store (32 lanes x 32B = 1KB contiguous per token)
    union { short8 v; unsigned short s[8]; } pa, pb;
    pa.s[0] = f2bf(xv[0].x); pa.s[1] = f2bf(xv[0].y); pa.s[2] = f2bf(xv[0].z); pa.s[3] = f2bf(xv[0].w);
    pa.s[4] = f2bf(xv[1].x); pa.s[5] = f2bf(xv[1].y); pa.s[6] = f2bf(xv[1].z); pa.s[7] = f2bf(xv[1].w);
    pb.s[0] = f2bf(xv[2].x); pb.s[1] = f2bf(xv[2].y); pb.s[2] = f2bf(xv[2].z); pb.s[3] = f2bf(xv[2].w);
    pb.s[4] = f2bf(xv[3].x); pb.s[5] = f2bf(xv[3].y); pb.s[6] = f2bf(xv[3].z); pb.s[7] = f2bf(xv[3].w);
    short8* xo = (short8*)(xbo + (size_t)n * HD + l32 * 16);
    xo[0] = pa.v; xo[1] = pb.v;

    float s[5];
#pragma unroll
    for (int e = 0; e < 5; e++) {
      s[e] = 0.f;
#pragma unroll
      for (int j = 0; j < 4; j++)
        s[e] += xv[j].x * wv[e][j].x + xv[j].y * wv[e][j].y
              + xv[j].z * wv[e][j].z + xv[j].w * wv[e][j].w;
    }
    // reduce within the 32-lane half (xor offsets stay inside the half)
#pragma unroll
    for (int off = 16; off > 0; off >>= 1)
#pragma unroll
      for (int i = 0; i < 5; i++) s[i] += __shfl_xor(s[i], off, 64);

    float m = fmaxf(fmaxf(s[0], s[1]), fmaxf(s[2], s[3]));
    float e0 = expf(s[0] - m), e1 = expf(s[1] - m), e2 = expf(s[2] - m), e3 = expf(s[3] - m);
    float inv = 1.f / (e0 + e1 + e2 + e3);
    float thr = 0.25f / (1.f + expf(-s[4]));
    float a0 = e0 * inv - thr, a1 = e1 * inv - thr, a2 = e2 * inv - thr, a3 = e3 * inv - thr;
    float w0 = a0 > 0.f ? a0 : 0.f, w1 = a1 > 0.f ? a1 : 0.f;
    float w2 = a2 > 0.f ? a2 : 0.f, w3 = a3 > 0.f ? a3 : 0.f;
    float wsum = w0 + w1 + w2 + w3;
    wsum = (wsum == 0.f) ? 1.f : wsum;
    if (l32 < 4) {
      float wval = l32 == 0 ? w0 : l32 == 1 ? w1 : l32 == 2 ? w2 : w3;
      gates[(size_t)n * 4 + l32] = wval / wsum;
    }
  }
}

// ---------------- merged prep: convk + prep_la + prep_mt (one launch) ----------------
// blocks [0,1024):    fc1_w fp32->bf16 (262144 float4)
// blocks [1024,1152): laT[e][r][h] = bf16(lora_A[e][h][r])
// blocks [1152,9344): Mt[d][e*16+r] = sum_o lora_B[e,r,o]*fc2_w[e,d,o], wave/output
__global__ void prep_all(const float* __restrict__ fc1w, unsigned short* __restrict__ w1b,
                         const float* __restrict__ la, unsigned short* __restrict__ laT,
                         const float* __restrict__ loraB, const float* __restrict__ fc2,
                         unsigned short* __restrict__ Mt) {
  const int bid = blockIdx.x, tid = threadIdx.x;
  if (bid < 1024) {
    int i = bid * 256 + tid;
    float4 v = ((const float4*)fc1w)[i];
    ushort4 u;
    u.x = f2bf(v.x); u.y = f2bf(v.y); u.z = f2bf(v.z); u.w = f2bf(v.w);
    ((ushort4*)w1b)[i] = u;
  } else if (bid < 1152) {
    int idx = (bid - 1024) * 256 + tid;       // 0..32767
    int h = idx & (HD - 1);
    int er = idx >> 9;                        // e*16+r
    int e = er >> 4, r = er & 15;
    laT[(size_t)er * HD + h] = f2bf(la[((size_t)e * HD + h) * RK + r]);
  } else {
    const int wid = (bid - 1152) * 4 + (tid >> 6);  // 0..32767
    const int lane = tid & 63;
    const int d = wid & (HD - 1);
    const int er = wid >> 9;
    const int e = er >> 4, r = er & 15;
    const float4* B = (const float4*)(loraB + ((size_t)e * RK + r) * HD);
    const float4* F = (const float4*)(fc2 + ((size_t)e * HD + d) * HD);
    const float4 b0 = B[lane * 2], b1 = B[lane * 2 + 1];
    const float4 f0 = F[lane * 2], f1 = F[lane * 2 + 1];
    float s = b0.x * f0.x + b0.y * f0.y + b0.z * f0.z + b0.w * f0.w
            + b1.x * f1.x + b1.y * f1.y + b1.z * f1.z + b1.w * f1.w;
#pragma unroll
    for (int off = 32; off > 0; off >>= 1) s += __shfl_xor(s, off, 64);
    if (lane == 0) Mt[d * 64 + er] = f2bf(s);
  }
}

// ---------------- fused fc1 + relu + lora_A -> lw[N][64] (atomic fp32) ----------------
// FROZEN from round 5 (m201-style schedule; three schedules all measure 166-170us,
// 37% MfmaUtil -> schedule exonerated, kept for attribution of aux changes).
__launch_bounds__(512, 2)
__global__ void fc1_lora(const unsigned short* __restrict__ xb,
                         const unsigned short* __restrict__ w1b,
                         const unsigned short* __restrict__ laT,
                         float* __restrict__ lw) {
  __shared__ __align__(16) char smem[135168];  // ring: 4x32768; epilogue hsm: 256x264x2
  const int bid = blockIdx.x;           // 2048 blocks
  const int c = bid & 7;                // XCD
  const int j = bid >> 3;               // 0..255 within XCD
  const int eh = j & 7;
  const int e = eh >> 1, hq = eh & 1;   // expert, h-half (256 h each)
  const int ntile = c * 32 + (j >> 3);
  const int n0 = ntile * 256;
  const int tid = threadIdx.x;
  const int wave = tid >> 6, lane = tid & 63;
  const int l16 = lane & 15, quad = lane >> 4;
  const int l32 = lane & 31, half = lane >> 5;
  const int wr = wave >> 2, wc = wave & 3;   // 2M x 4N wave grid (each 128x64 out)

  const unsigned short* xg = xb + (size_t)n0 * HD;
  const unsigned short* wg = w1b + ((size_t)e * HD + (size_t)hq * 256) * HD;

  const unsigned short* xsrc[2];
  const unsigned short* wsrc[2];
#pragma unroll
  for (int i = 0; i < 2; i++) {
    const int sl = tid + 512 * i;
    const int sr = sl >> 3, g8 = (sl & 7) ^ (sr & 7);
    const int row = sr * 2 + (g8 >> 2), g = g8 & 3;
    xsrc[i] = xg + (size_t)row * HD + g * 8;
    wsrc[i] = wg + (size_t)row * HD + g * 8;
  }
  const int wbase = wave * 1024;

  int axo[2][4], bxo[2][2];
#pragma unroll
  for (int p = 0; p < 2; p++) {
#pragma unroll
    for (int mb = 0; mb < 4; mb++) {
      const int rowa = wr * 128 + mb * 32 + l32;
      const int sr = rowa >> 1, g8 = (rowa & 1) * 4 + p * 2 + half;
      axo[p][mb] = (sr * 8 + (g8 ^ (sr & 7))) * 16;
    }
#pragma unroll
    for (int nb = 0; nb < 2; nb++) {
      const int rowb = wc * 64 + nb * 32 + l32;
      const int sr = rowb >> 1, g8 = (rowb & 1) * 4 + p * 2 + half;
      bxo[p][nb] = (sr * 8 + (g8 ^ (sr & 7))) * 16;
    }
  }

  f32x16 acc[4][2];
#pragma unroll
  for (int mb = 0; mb < 4; mb++)
#pragma unroll
    for (int nb = 0; nb < 2; nb++)
#pragma unroll
      for (int r = 0; r < 16; r++) acc[mb][nb][r] = 0.f;

#pragma unroll
  for (int tt = 0; tt < 3; tt++) {
    char* As = smem + tt * 32768;
#pragma unroll
    for (int i = 0; i < 2; i++) gl_lds16(xsrc[i] + tt * 32, As + wbase + 8192 * i);
#pragma unroll
    for (int i = 0; i < 2; i++) gl_lds16(wsrc[i] + tt * 32, As + 16384 + wbase + 8192 * i);
  }
  asm volatile("s_waitcnt vmcnt(8)" ::: "memory");
  __builtin_amdgcn_s_barrier();
  __builtin_amdgcn_sched_barrier(0);

#pragma unroll
  for (int t = 0; t < 16; t++) {
    char* Ab = smem + (t & 3) * 32768;
    char* Bb = Ab + 16384;
    char* As = smem + ((t + 3) & 3) * 32768;
    const int kos = (t + 3) * 32;
#pragma unroll
    for (int p = 0; p < 2; p++) {
      short8 af[4], bf[2];
#pragma unroll
      for (int mb = 0; mb < 4; mb++) af[mb] = *(const short8*)(Ab + axo[p][mb]);
#pragma unroll
      for (int nb = 0; nb < 2; nb++) bf[nb] = *(const short8*)(Bb + bxo[p][nb]);
      if (t < 13) {
        gl_lds16(xsrc[p] + kos, As + wbase + 8192 * p);
        gl_lds16(wsrc[p] + kos, As + 16384 + wbase + 8192 * p);
      }
      __builtin_amdgcn_s_barrier();
      asm volatile("s_waitcnt lgkmcnt(0)" ::: "memory");
      __builtin_amdgcn_sched_barrier(0);
      __builtin_amdgcn_s_setprio(1);
#pragma unroll
      for (int mb = 0; mb < 4; mb++)
#pragma unroll
        for (int nb = 0; nb < 2; nb++)
          acc[mb][nb] = __builtin_amdgcn_mfma_f32_32x32x16_bf16(af[mb], bf[nb], acc[mb][nb], 0, 0, 0);
      __builtin_amdgcn_s_setprio(0);
      if (p == 0) {
        __builtin_amdgcn_s_barrier();
      } else {
        if (t < 13)       asm volatile("s_waitcnt vmcnt(8)" ::: "memory");
        else if (t == 13) asm volatile("s_waitcnt vmcnt(4)" ::: "memory");
        else if (t == 14) asm volatile("s_waitcnt vmcnt(0)" ::: "memory");
        __builtin_amdgcn_s_barrier();
      }
      __builtin_amdgcn_sched_barrier(0);
    }
  }

  unsigned short* hsm = (unsigned short*)smem;
#pragma unroll
  for (int mb = 0; mb < 4; mb++)
#pragma unroll
    for (int nb = 0; nb < 2; nb++) {
      const int colh = wc * 64 + nb * 32 + l32;
#pragma unroll
      for (int r = 0; r < 16; r++) {
        const int tok = wr * 128 + mb * 32 + 4 * half + (r & 3) + 8 * (r >> 2);
        float v = acc[mb][nb][r];
        v = v > 0.f ? v : 0.f;
        hsm[tok * 264 + colh] = f2bf(v);
      }
    }
  __syncthreads();

  const unsigned short* laTe = laT + (size_t)(e * 16 + l16) * HD + hq * 256;
  f32x4 lo[2];
#pragma unroll
  for (int mf = 0; mf < 2; mf++)
#pragma unroll
    for (int i = 0; i < 4; i++) lo[mf][i] = 0.f;
#pragma unroll
  for (int k2 = 0; k2 < 8; k2++) {
    const short8 b2 = *(const short8*)(laTe + k2 * 32 + quad * 8);
#pragma unroll
    for (int mf = 0; mf < 2; mf++) {
      const int tok = wave * 32 + mf * 16 + l16;
      const short8 a2 = *(const short8*)(hsm + tok * 264 + k2 * 32 + quad * 8);
      lo[mf] = __builtin_amdgcn_mfma_f32_16x16x32_bf16(a2, b2, lo[mf], 0, 0, 0);
    }
  }
#pragma unroll
  for (int mf = 0; mf < 2; mf++)
#pragma unroll
    for (int i = 0; i < 4; i++)
      atomicAdd(lw + (size_t)(n0 + wave * 32 + mf * 16 + quad * 4 + i) * 64 + e * 16 + l16, lo[mf][i]);
}

// ---------------- combine: out[n][d] = sum_k (lw[n][k]*gate[n][k/16]) * Mt[d][k] ----------------
// FROZEN from round 5.
__launch_bounds__(256, 2)
__global__ void combine_k(const float* __restrict__ lw, const float* __restrict__ gates,
                          const unsigned short* __restrict__ Mt, float* __restrict__ out) {
  __shared__ __align__(16) char smem[65536];
  const int n0 = blockIdx.x * 64;
  const int tid = threadIdx.x;
  const int wave = tid >> 6, lane = tid & 63, quad = lane >> 4, l16 = lane & 15;
#pragma unroll
  for (int i = 0; i < 16; i++) {
    const int slot = tid + 256 * i;          // 0..4095
    const int row = slot >> 3;
    const int g = (slot & 7) ^ (row & 7);
    *(uint4*)(smem + slot * 16) = *(const uint4*)(Mt + row * 64 + g * 8);
  }
  __syncthreads();
  f32x4 acc[4][8];
#pragma unroll
  for (int a = 0; a < 4; a++)
#pragma unroll
    for (int b = 0; b < 8; b++)
#pragma unroll
      for (int i = 0; i < 4; i++) acc[a][b][i] = 0.f;
#pragma unroll
  for (int ks = 0; ks < 2; ks++) {
    short8 af[4], bfr[8];
#pragma unroll
    for (int mf = 0; mf < 4; mf++) {
      const int n = n0 + mf * 16 + l16;
      const float* lr = lw + (size_t)n * 64 + ks * 32 + quad * 8;
      float4 u0 = *(const float4*)lr;
      float4 u1 = *(const float4*)(lr + 4);
      const float g = gates[(size_t)n * 4 + ((ks * 32 + quad * 8) >> 4)];
      union { short8 v; unsigned short s[8]; } a;
      a.s[0] = f2bf(u0.x * g); a.s[1] = f2bf(u0.y * g);
      a.s[2] = f2bf(u0.z * g); a.s[3] = f2bf(u0.w * g);
      a.s[4] = f2bf(u1.x * g); a.s[5] = f2bf(u1.y * g);
      a.s[6] = f2bf(u1.z * g); a.s[7] = f2bf(u1.w * g);
      af[mf] = a.v;
    }
#pragma unroll
    for (int nf = 0; nf < 8; nf++) {
      const int row = wave * 128 + nf * 16 + l16;
      const int slot = row * 8 + ((ks * 4 + quad) ^ (row & 7));
      bfr[nf] = *(const short8*)(smem + slot * 16);
    }
#pragma unroll
    for (int mf = 0; mf < 4; mf++)
#pragma unroll
      for (int nf = 0; nf < 8; nf++)
        acc[mf][nf] = __builtin_amdgcn_mfma_f32_16x16x32_bf16(af[mf], bfr[nf], acc[mf][nf], 0, 0, 0);
  }
  __syncthreads();
  float* scr = (float*)smem + wave * 320;   // [16][20] f32
#pragma unroll
  for (int mf = 0; mf < 4; mf++)
#pragma unroll
    for (int nf = 0; nf < 8; nf++) {
#pragma unroll
      for (int i = 0; i < 4; i++) scr[(quad * 4 + i) * 20 + l16] = acc[mf][nf][i];
      float4 v = *(const float4*)(scr + l16 * 20 + quad * 4);
      *(float4*)(out + (size_t)(n0 + mf * 16 + l16) * HD + wave * 128 + nf * 16 + quad * 4) = v;
    }
}

// ---------------- launch ----------------
extern "C" void kernel_launch(void* const* d_in, const int* in_sizes, int n_in,
                              void* d_out, int out_size, void* d_ws, size_t ws_size,
                              hipStream_t stream) {
  const float* x      = (const float*)d_in[0];
  const float* gate_w = (const float*)d_in[1];
  const float* thr_w  = (const float*)d_in[2];
  const float* fc1_w  = (const float*)d_in[3];
  const float* lora_A = (const float*)d_in[4];
  const float* lora_B = (const float*)d_in[5];
  const float* fc2_w  = (const float*)d_in[6];
  float* out = (float*)d_out;
  char* ws = (char*)d_ws;

  unsigned short* xbp = (unsigned short*)(ws);                   // 67108864 B
  unsigned short* w1b = (unsigned short*)(ws + 67108864);        //  2097152 B
  unsigned short* Mt  = (unsigned short*)(ws + 69206016);        //    65536 B
  float*          gts = (float*)(ws + 69271552);                 //  1048576 B
  float*          lwp = (float*)(ws + 70320128);                 // 16777216 B
  unsigned short* laT = (unsigned short*)(ws + 87097344);        //    65536 B

  hipMemsetAsync(lwp, 0, (size_t)NTOK * 64 * sizeof(float), stream);
  convgate<<<NTOK / 32, 256, 0, stream>>>(x, gate_w, thr_w, xbp, gts);
  prep_all<<<9344, 256, 0, stream>>>(fc1_w, w1b, lora_A, laT, lora_B, fc2_w, Mt);
  fc1_lora<<<2048, 512, 0, stream>>>(xbp, w1b, laT, lwp);
  combine_k<<<NTOK / 64, 256, 0, stream>>>(lwp, gts, Mt, out);
}